// Round 8
// baseline (437.384 us; speedup 1.0000x reference)
//
#include <hip/hip_runtime.h>
#include <hip/hip_bf16.h>

#define BB 16
#define SS 2048
#define DD 64
#define NT (SS / 64)

typedef __attribute__((ext_vector_type(8)))  unsigned short ushort8;
typedef __attribute__((ext_vector_type(8)))  __bf16 bf16x8;
typedef __attribute__((ext_vector_type(16))) float f32x16;

static __device__ __forceinline__ unsigned short f2bf(float x) {
    return __builtin_bit_cast(unsigned short, __float2bfloat16(x));
}
static __device__ __forceinline__ unsigned pk2f(float a, float b) {
    return (unsigned)f2bf(a) | ((unsigned)f2bf(b) << 16);
}
union F4 { float4 v; float a[4]; };

// bf16 MFMA attention, 32x32x16 tiles, BARRIER-FREE K-loop.
// r7 post-mortem: __syncthreads drains vmcnt -> prefetch dead. Fix: no LDS
// sharing inside the loop. K -> per-lane regs (A-frag is lane-local in
// global). Mask -> per-lane regs (ping-pong, 1 iter of prefetch depth).
// V -> wave-private LDS tile (same-wave in-order DS replaces the barrier).
// Compute core (S^T = K*Q^T, shfl_xor(32) P exchange, O^T = V^T*P^T) is
// byte-identical to the proven r5/r7 kernel. Mask = int32 words (proven r4).
// No max-subtraction: logits bounded; masked -> p = 1.0f exactly.
__global__ __launch_bounds__(256, 2)
void sdpa_mfma_kernel(const float* __restrict__ Q, const float* __restrict__ K,
                      const float* __restrict__ V, const unsigned int* __restrict__ M,
                      float* __restrict__ O) {
    // smem: Qs 8192 | 4 wave-private V^T tiles (64 d-rows, pitch 80, swizzled)
    __shared__ __align__(16) char smem[8192 + 4 * 5120];
    char* Qs = smem;

    const int t    = threadIdx.x;
    const int lane = t & 63;
    const int l31  = lane & 31;
    const int half = lane >> 5;
    const int w    = t >> 6;
    const int qs   = w & 1;    // q-subtile
    const int kh   = w >> 1;   // k-split half
    const int b    = blockIdx.y;
    const int q0   = blockIdx.x * 64;
    char* Vw = smem + 8192 + w * 5120;   // this wave's private V^T tile

    const float* Qg = Q + ((size_t)b * SS + q0) * DD;
    const float* Kg = K + (size_t)b * SS * DD;
    const float* Vg = V + (size_t)b * SS * DD;
    const unsigned int* Mg = M + (size_t)b * SS * SS + (size_t)q0 * SS;

    const int gk  = lane >> 4;          // V staging: k-granule (8 rows)
    const int d0v = (lane & 15) * 4;    // V staging: d columns
    // lane-private global base pointers (advance by kt*4096 floats / kt*64 words)
    const float* kp = Kg + (size_t)(32 * kh + l31) * DD + 8 * half;
    const float* vp = Vg + (size_t)(32 * kh + 8 * gk) * DD + d0v;
    const unsigned int* mp = Mg + (size_t)(32 * qs + l31) * SS + 32 * kh + 4 * half;

    F4 kf[8], vf[8];
    uint4 mfA[4], mfB[4];

    // ---- prologue: issue tile-0 loads before Q staging (latency cover) ----
    #pragma unroll
    for (int dc = 0; dc < 4; dc++) {
        kf[2 * dc].v     = *(const float4*)(kp + 16 * dc);
        kf[2 * dc + 1].v = *(const float4*)(kp + 16 * dc + 4);
    }
    #pragma unroll
    for (int r = 0; r < 8; r++) vf[r].v = *(const float4*)(vp + r * DD);
    #pragma unroll
    for (int g = 0; g < 4; g++) mfA[g] = *(const uint4*)(mp + 8 * g);

    // ---- stage Q (pre-scaled by 1/temperature), swizzled bf16 ----
    {
        const int sr = t >> 2, scm = t & 3;
        F4 f0, f1, f2, f3;
        const float* src = Qg + sr * DD + scm * 16;
        f0.v = *(const float4*)(src);
        f1.v = *(const float4*)(src + 4);
        f2.v = *(const float4*)(src + 8);
        f3.v = *(const float4*)(src + 12);
        ushort8 u0, u1;
        #pragma unroll
        for (int e = 0; e < 4; e++) {
            u0[e]     = f2bf(f0.a[e] * 0.125f);
            u0[e + 4] = f2bf(f1.a[e] * 0.125f);
            u1[e]     = f2bf(f2.a[e] * 0.125f);
            u1[e + 4] = f2bf(f3.a[e] * 0.125f);
        }
        *(ushort8*)(Qs + sr * 128 + (((scm * 2)     ^ (sr & 7)) * 16)) = u0;
        *(ushort8*)(Qs + sr * 128 + (((scm * 2 + 1) ^ (sr & 7)) * 16)) = u1;
    }
    __syncthreads();   // the only pre-epilogue barrier

    // ---- preload Q fragments (B operand), registers for whole loop ----
    const int qrow = 32 * qs + l31;
    bf16x8 bq[4];
    #pragma unroll
    for (int dc = 0; dc < 4; dc++)
        bq[dc] = __builtin_bit_cast(bf16x8, *(const ushort8*)(
            Qs + qrow * 128 + (((2 * dc + half) ^ (qrow & 7)) * 16)));

    f32x16 On0, On1;
    #pragma unroll
    for (int i = 0; i < 16; i++) { On0[i] = 0.f; On1[i] = 0.f; }
    float den_acc = 0.f;

#define ITER(MC, MN, KT) do {                                                  \
    const int ktn_ = ((KT) + 1 < NT) ? (KT) + 1 : NT - 1;                      \
    /* 1. mask prefetch for next tile (1 full iter of latency depth) */        \
    {                                                                          \
        const unsigned int* mpp_ = mp + (size_t)ktn_ * 64;                     \
        _Pragma("unroll")                                                      \
        for (int g = 0; g < 4; g++) MN[g] = *(const uint4*)(mpp_ + 8 * g);     \
    }                                                                          \
    /* 2. cvt K regs (tile KT) -> A fragments */                               \
    bf16x8 ak_[4];                                                             \
    _Pragma("unroll")                                                          \
    for (int dc = 0; dc < 4; dc++) {                                           \
        ushort8 u_;                                                            \
        _Pragma("unroll")                                                      \
        for (int e = 0; e < 4; e++) {                                          \
            u_[e]     = f2bf(kf[2 * dc].a[e]);                                 \
            u_[e + 4] = f2bf(kf[2 * dc + 1].a[e]);                             \
        }                                                                      \
        ak_[dc] = __builtin_bit_cast(bf16x8, u_);                              \
    }                                                                          \
    /* 3. QK^T: S^T tile [32k x 32q] */                                        \
    f32x16 S_;                                                                 \
    _Pragma("unroll")                                                          \
    for (int i = 0; i < 16; i++) S_[i] = 0.f;                                  \
    _Pragma("unroll")                                                          \
    for (int dc = 0; dc < 4; dc++)                                             \
        S_ = __builtin_amdgcn_mfma_f32_32x32x16_bf16(ak_[dc], bq[dc], S_, 0, 0, 0); \
    /* 4. mask + exp + den (C row = e + 8g + 4half) */                         \
    float p_[16];                                                              \
    _Pragma("unroll")                                                          \
    for (int g = 0; g < 4; g++) {                                              \
        const unsigned mw_[4] = {MC[g].x, MC[g].y, MC[g].z, MC[g].w};          \
        _Pragma("unroll")                                                      \
        for (int e = 0; e < 4; e++) {                                          \
            const float ev_ = __expf(S_[4 * g + e]);                           \
            const float pv_ = mw_[e] ? 1.0f : ev_;                             \
            p_[4 * g + e] = pv_;                                               \
            den_acc += pv_;                                                    \
        }                                                                      \
    }                                                                          \
    /* 5. V regs (tile KT) -> wave-private LDS (V^T, pitch 80, swizzled) */    \
    _Pragma("unroll")                                                          \
    for (int e = 0; e < 4; e++) {                                              \
        const int d_ = d0v + e;                                                \
        uint4 pkv_;                                                            \
        pkv_.x = pk2f(vf[0].a[e], vf[1].a[e]);                                 \
        pkv_.y = pk2f(vf[2].a[e], vf[3].a[e]);                                 \
        pkv_.z = pk2f(vf[4].a[e], vf[5].a[e]);                                 \
        pkv_.w = pk2f(vf[6].a[e], vf[7].a[e]);                                 \
        *(uint4*)(Vw + d_ * 80 + (((gk ^ (d_ >> 2)) & 3) * 16)) = pkv_;        \
    }                                                                          \
    /* 6. K,V loads for next tile (regs now free) */                           \
    {                                                                          \
        const float* kpp_ = kp + (size_t)ktn_ * 4096;                          \
        _Pragma("unroll")                                                      \
        for (int dc = 0; dc < 4; dc++) {                                       \
            kf[2 * dc].v     = *(const float4*)(kpp_ + 16 * dc);               \
            kf[2 * dc + 1].v = *(const float4*)(kpp_ + 16 * dc + 4);           \
        }                                                                      \
        const float* vpp_ = vp + (size_t)ktn_ * 4096;                          \
        _Pragma("unroll")                                                      \
        for (int r = 0; r < 8; r++) vf[r].v = *(const float4*)(vpp_ + r * DD); \
    }                                                                          \
    /* 7. P exchange via shfl_xor(32) (proven r5) + PV */                      \
    _Pragma("unroll")                                                          \
    for (int s2 = 0; s2 < 2; s2++) {                                           \
        const unsigned o0 = pk2f(p_[8 * s2 + 0], p_[8 * s2 + 1]);              \
        const unsigned o1 = pk2f(p_[8 * s2 + 2], p_[8 * s2 + 3]);              \
        const unsigned o2 = pk2f(p_[8 * s2 + 4], p_[8 * s2 + 5]);              \
        const unsigned o3 = pk2f(p_[8 * s2 + 6], p_[8 * s2 + 7]);              \
        const unsigned s0 = half ? o0 : o2;                                    \
        const unsigned s1 = half ? o1 : o3;                                    \
        const unsigned r0 = (unsigned)__shfl_xor((int)s0, 32, 64);             \
        const unsigned r1 = (unsigned)__shfl_xor((int)s1, 32, 64);             \
        uint4 bu;                                                              \
        bu.x = half ? r0 : o0;                                                 \
        bu.y = half ? r1 : o1;                                                 \
        bu.z = half ? o2 : r0;                                                 \
        bu.w = half ? o3 : r1;                                                 \
        const bf16x8 bp = __builtin_bit_cast(bf16x8, bu);                      \
        _Pragma("unroll")                                                      \
        for (int dc2 = 0; dc2 < 2; dc2++) {                                    \
            const int vrow = 32 * dc2 + l31;                                   \
            bf16x8 av = __builtin_bit_cast(bf16x8, *(const ushort8*)(          \
                Vw + vrow * 80 + ((((2 * s2 + half) ^ (vrow >> 2)) & 3) * 16))); \
            if (dc2 == 0) On0 = __builtin_amdgcn_mfma_f32_32x32x16_bf16(av, bp, On0, 0, 0, 0); \
            else          On1 = __builtin_amdgcn_mfma_f32_32x32x16_bf16(av, bp, On1, 0, 0, 0); \
        }                                                                      \
    }                                                                          \
} while (0)

    for (int kt = 0; kt < NT; kt += 2) {
        ITER(mfA, mfB, kt);
        ITER(mfB, mfA, kt + 1);
    }
#undef ITER

    // ---- epilogue: lane halves, then the two k-split waves ----
    const float den_tot = den_acc + __shfl_xor(den_acc, 32, 64);
    float* red  = (float*)smem;             // 16 KB scratch (loop LDS dead)
    float* denx = (float*)(smem + 16384);

    __syncthreads();
    if (kh == 1) {
        #pragma unroll
        for (int dc = 0; dc < 2; dc++)
            #pragma unroll
            for (int g = 0; g < 4; g++) {
                const f32x16& Oc = dc ? On1 : On0;
                float4 st;
                st.x = Oc[4 * g + 0]; st.y = Oc[4 * g + 1];
                st.z = Oc[4 * g + 2]; st.w = Oc[4 * g + 3];
                *(float4*)((char*)red + qs * 8192 + (dc * 4 + g) * 1024 + lane * 16) = st;
            }
        if (lane < 32) denx[qs * 32 + l31] = den_tot;
    }
    __syncthreads();
    if (kh == 0) {
        const float inv = 1.0f / (den_tot + denx[qs * 32 + l31]);
        float* Og = O + ((size_t)b * SS + q0 + qrow) * DD;
        #pragma unroll
        for (int dc = 0; dc < 2; dc++)
            #pragma unroll
            for (int g = 0; g < 4; g++) {
                const float4 pr = *(const float4*)((char*)red + qs * 8192 + (dc * 4 + g) * 1024 + lane * 16);
                const f32x16& Oc = dc ? On1 : On0;
                float4 st;
                st.x = (Oc[4 * g + 0] + pr.x) * inv;
                st.y = (Oc[4 * g + 1] + pr.y) * inv;
                st.z = (Oc[4 * g + 2] + pr.z) * inv;
                st.w = (Oc[4 * g + 3] + pr.w) * inv;
                // d = e + 8g + 4half + 32dc  (C-row formula)
                *(float4*)(Og + 32 * dc + 8 * g + 4 * half) = st;
            }
    }
}

extern "C" void kernel_launch(void* const* d_in, const int* in_sizes, int n_in,
                              void* d_out, int out_size, void* d_ws, size_t ws_size,
                              hipStream_t stream) {
    const float* q = (const float*)d_in[0];
    const float* k = (const float*)d_in[1];
    const float* v = (const float*)d_in[2];
    const unsigned int* m = (const unsigned int*)d_in[3];
    float* out = (float*)d_out;

    dim3 grid(SS / 64, BB);   // 32 x 16 = 512 blocks -> exactly 2 per CU
    sdpa_mfma_kernel<<<grid, 256, 0, stream>>>(q, k, v, m, out);
}